// Round 1
// baseline (409.008 us; speedup 1.0000x reference)
//
#include <hip/hip_runtime.h>

// VectorQuantiser forward, MI355X fp32 implementation.
// N=65536 tokens (16x64x64, channel dim 64 strided by 4096), K=1024 codes, D=64.
//
// Numerical strategy: replicate numpy-fp32 op-for-op where rounding decides
// argmax ties (zn2 pairwise sum, d composition); free order where it doesn't
// (dot products, large mean reductions in fp64).

#define N_TOK   65536
#define K_CODES 1024
#define KP      4     // k partitions in k_scores
#define KCHUNK  256   // codes per partition

// ---- ws layout (bytes) ----
// [0, 524288)        u64 wsrow[65536]   packed (ord(val)<<32)|~k   row argmax
// [524288, 532480)   u64 wscol[1024]    packed (ord(val)<<32)|~n   col argmax
// [532480, 536576)   u32 counts[1024]
// [536576, 536584)   double loss_acc
// [536592, 540688)   float en2[1024]
#define WS_ROW   0
#define WS_COL   524288
#define WS_CNT   532480
#define WS_LOSS  536576
#define WS_EN2   536592
#define WS_BYTES 540688

__device__ __forceinline__ unsigned int f32_ord(float x) {
    unsigned int b = __float_as_uint(x);
    return (b & 0x80000000u) ? ~b : (b | 0x80000000u);
}

// numpy pairwise sum of squares over 64 contiguous elements:
// r[j] = a[j]^2 + a[8+j]^2 + ... + a[56+j]^2 (sequential), then
// ((r0+r1)+(r2+r3)) + ((r4+r5)+(r6+r7)). All fp32, no contraction.
template <typename F>
__device__ __forceinline__ float np_pairwise64_sq(F get) {
    float r[8];
#pragma unroll
    for (int j = 0; j < 8; ++j) {
        float v = get(j);
        r[j] = __fmul_rn(v, v);
    }
#pragma unroll
    for (int i = 8; i < 64; i += 8) {
#pragma unroll
        for (int j = 0; j < 8; ++j) {
            float v = get(i + j);
            r[j] = __fadd_rn(r[j], __fmul_rn(v, v));
        }
    }
    return __fadd_rn(__fadd_rn(__fadd_rn(r[0], r[1]), __fadd_rn(r[2], r[3])),
                     __fadd_rn(__fadd_rn(r[4], r[5]), __fadd_rn(r[6], r[7])));
}

// ---- K0: codebook squared norms (np-pairwise replicated) ----
__global__ __launch_bounds__(256) void k_en2(const float* __restrict__ emb,
                                             float* __restrict__ en2) {
    int k = blockIdx.x * 256 + threadIdx.x;
    const float* a = emb + (size_t)k * 64;
    en2[k] = np_pairwise64_sq([&](int i) { return a[i]; });
}

// ---- K1: score matrix + row/col argmax ----
// grid (256 token-blocks, KP partitions), block 256 (thread = 1 token).
__global__ __launch_bounds__(256) void k_scores(
    const float* __restrict__ z, const float* __restrict__ emb,
    const float* __restrict__ en2,
    unsigned long long* __restrict__ wsrow,
    unsigned long long* __restrict__ wscol) {
    const int t    = threadIdx.x;
    const int n    = blockIdx.x * 256 + t;
    const int k0   = blockIdx.y * KCHUNK;
    const int b    = n >> 12;
    const int hw   = n & 4095;
    const int lane = t & 63;
    const int wave = t >> 6;

    const float* zp = z + (size_t)b * 262144 + hw;
    float zr[64];
#pragma unroll
    for (int c = 0; c < 64; ++c) zr[c] = zp[(size_t)c * 4096];

    const float nzn2 = -np_pairwise64_sq([&](int i) { return zr[i]; });

    __shared__ unsigned long long lred[4][64];

    float bestv = -3.4e38f;
    int   bestk = 0;

    const float4* E4 = reinterpret_cast<const float4*>(emb);

    for (int s = 0; s < 4; ++s) {
        unsigned long long myslot = 0ull;
        for (int kk = 0; kk < 64; ++kk) {
            const int k = k0 + s * 64 + kk;
            // dot(z_n, e_k): order-free, 4 chains. e loads are wave-uniform
            // -> scalar (s_load) path, SGPR operand into v_fmac.
            const float4* ek = E4 + (size_t)k * 16;
            float c0 = 0.f, c1 = 0.f, c2 = 0.f, c3 = 0.f;
#pragma unroll
            for (int j = 0; j < 16; ++j) {
                float4 e = ek[j];
                c0 = fmaf(e.x, zr[4 * j + 0], c0);
                c1 = fmaf(e.y, zr[4 * j + 1], c1);
                c2 = fmaf(e.z, zr[4 * j + 2], c2);
                c3 = fmaf(e.w, zr[4 * j + 3], c3);
            }
            float dot = (c0 + c1) + (c2 + c3);
            // d = ((-zn2) - en2) + 2*dot, fp32 per-op like the reference
            float d = __fadd_rn(__fsub_rn(nzn2, en2[k]), 2.0f * dot);

            // row argmax over k: strict >, ascending k == first-index ties
            if (d > bestv) { bestv = d; bestk = k; }

            // column argmax over n within the wave: value butterfly + ballot.
            float m = d;
#pragma unroll
            for (int off = 32; off; off >>= 1)
                m = fmaxf(m, __shfl_xor(m, off, 64));
            unsigned long long msk = __ballot(d == m);
            int winlane = __ffsll((unsigned long long)msk) - 1;  // lowest lane = lowest n
            if (kk == lane) {
                int winn = blockIdx.x * 256 + wave * 64 + winlane;
                myslot = ((unsigned long long)f32_ord(m) << 32) |
                         (unsigned long long)(unsigned int)(~(unsigned int)winn);
            }
        }
        // merge 4 waves' winners for this 64-code slot, one atomic per code
        lred[wave][lane] = myslot;
        __syncthreads();
        if (t < 64) {
            unsigned long long mm = lred[0][t];
#pragma unroll
            for (int w = 1; w < 4; ++w) {
                unsigned long long o = lred[w][t];
                mm = (o > mm) ? o : mm;
            }
            atomicMax(&wscol[k0 + s * 64 + t], mm);
        }
        __syncthreads();
    }

    unsigned long long rowkey =
        ((unsigned long long)f32_ord(bestv) << 32) |
        (unsigned long long)(unsigned int)(~(unsigned int)bestk);
    atomicMax(&wsrow[n], rowkey);
}

// ---- K2: per-token outputs: z_q (straight-through), indices, hist, loss ----
__global__ __launch_bounds__(256) void k_tokens(
    const float* __restrict__ z, const float* __restrict__ emb,
    const unsigned long long* __restrict__ wsrow,
    unsigned int* __restrict__ counts, double* __restrict__ loss_acc,
    float* __restrict__ out_zq, float* __restrict__ out_idx) {
    const int n  = blockIdx.x * 256 + threadIdx.x;
    const int b  = n >> 12;
    const int hw = n & 4095;

    unsigned long long key = wsrow[n];
    int idx = (int)(~(unsigned int)(key & 0xFFFFFFFFull));
    out_idx[n] = (float)idx;
    atomicAdd(&counts[idx], 1u);

    const float* zp = z + (size_t)b * 262144 + hw;
    float*       op = out_zq + (size_t)b * 262144 + hw;
    const float* ep = emb + (size_t)idx * 64;

    double ls = 0.0;
#pragma unroll
    for (int c = 0; c < 64; ++c) {
        float zc   = zp[(size_t)c * 4096];
        float eq   = ep[c];
        float diff = __fsub_rn(eq, zc);           // fl(z_q - zc)
        float sq   = __fmul_rn(diff, diff);       // fl(diff^2), loss term
        ls += (double)sq;
        op[(size_t)c * 4096] = __fadd_rn(zc, diff);  // zc + fl(z_q - zc)
    }

    __shared__ double sred[256];
    sred[threadIdx.x] = ls;
    __syncthreads();
    for (int st = 128; st; st >>= 1) {
        if (threadIdx.x < st) sred[threadIdx.x] += sred[threadIdx.x + st];
        __syncthreads();
    }
    if (threadIdx.x == 0) atomicAdd(loss_acc, sred[0]);
}

// ---- K3: per-code outputs: perplexity, loss scalar, probs, new embedding ----
__global__ __launch_bounds__(1024) void k_codes(
    const float* __restrict__ z, const float* __restrict__ emb,
    const float* __restrict__ embed_prob,
    const unsigned long long* __restrict__ wscol,
    const unsigned int* __restrict__ counts,
    const double* __restrict__ loss_acc,
    float* __restrict__ out_loss, float* __restrict__ out_perp,
    float* __restrict__ out_newemb, float* __restrict__ out_prob) {
    const int k = threadIdx.x;  // one block of 1024

    float avg  = (float)counts[k] * (1.0f / 65536.0f);  // exact: /2^16
    float pnew = __fadd_rn(__fmul_rn(embed_prob[k], 0.99f),
                           __fmul_rn(0.01f, avg));
    out_prob[k] = pnew;

    // entropy term, fp32 elementwise then fp64 tree sum
    float term = __fmul_rn(avg, logf(__fadd_rn(avg, 1e-10f)));
    __shared__ double red[1024];
    red[k] = (double)term;
    __syncthreads();
    for (int st = 512; st; st >>= 1) {
        if (k < st) red[k] += red[k + st];
        __syncthreads();
    }
    if (k == 0) {
        float s32 = (float)red[0];
        out_perp[0] = expf(-s32);
        double lm = loss_acc[0] / 4194304.0;
        float  m  = (float)lm;
        out_loss[0] = __fadd_rn(__fmul_rn(0.25f, m), m);  // BETA*m + m
    }

    // decay = exp(-(pnew*1024*10)/0.01 - 1e-3)
    float tt = __fdiv_rn(__fmul_rn(__fmul_rn(pnew, 1024.0f), 10.0f), 0.01f);
    float ex = __fsub_rn(-tt, 1e-3f);
    float dk = expf(ex);
    float omd = __fsub_rn(1.0f, dk);

    unsigned long long ck = wscol[k];
    int cn  = (int)(~(unsigned int)(ck & 0xFFFFFFFFull));
    int cb  = cn >> 12;
    int chw = cn & 4095;
    const float* zp = z + (size_t)cb * 262144 + chw;

#pragma unroll 4
    for (int c = 0; c < 64; ++c) {
        float rf = zp[(size_t)c * 4096];
        float e  = emb[(size_t)k * 64 + c];
        out_newemb[(size_t)k * 64 + c] =
            __fadd_rn(__fmul_rn(e, omd), __fmul_rn(rf, dk));
    }
}

extern "C" void kernel_launch(void* const* d_in, const int* in_sizes, int n_in,
                              void* d_out, int out_size, void* d_ws, size_t ws_size,
                              hipStream_t stream) {
    const float* z    = (const float*)d_in[0];   // 16*64*64*64
    const float* emb  = (const float*)d_in[1];   // 1024*64
    const float* prob = (const float*)d_in[2];   // 1024

    float* out        = (float*)d_out;
    float* out_zq     = out;                 // 4194304
    float* out_loss   = out + 4194304;       // 1
    float* out_perp   = out + 4194305;       // 1
    float* out_newemb = out + 4194306;       // 65536
    float* out_prob   = out + 4259842;       // 1024
    float* out_idx    = out + 4260866;       // 65536

    char* ws = (char*)d_ws;
    unsigned long long* wsrow = (unsigned long long*)(ws + WS_ROW);
    unsigned long long* wscol = (unsigned long long*)(ws + WS_COL);
    unsigned int*       cnts  = (unsigned int*)(ws + WS_CNT);
    double*             lacc  = (double*)(ws + WS_LOSS);
    float*              en2   = (float*)(ws + WS_EN2);

    hipMemsetAsync(d_ws, 0, WS_BYTES, stream);

    hipLaunchKernelGGL(k_en2, dim3(4), dim3(256), 0, stream, emb, en2);
    hipLaunchKernelGGL(k_scores, dim3(256, KP), dim3(256), 0, stream,
                       z, emb, en2, wsrow, wscol);
    hipLaunchKernelGGL(k_tokens, dim3(256), dim3(256), 0, stream,
                       z, emb, wsrow, cnts, lacc, out_zq, out_idx);
    hipLaunchKernelGGL(k_codes, dim3(1), dim3(1024), 0, stream,
                       z, emb, prob, wscol, cnts, lacc,
                       out_loss, out_perp, out_newemb, out_prob);
}

// Round 2
// 258.819 us; speedup vs baseline: 1.5803x; 1.5803x over previous
//
#include <hip/hip_runtime.h>

// VectorQuantiser forward, MI355X fp32.
// N=65536 tokens (16x64x64, channel dim 64 strided by 4096), K=1024 codes, D=64.
//
// Round 2: k_scores restructured — per-wave LDS d-tile column reduction
// (replaces 6-deep ds_bpermute butterfly per code), __launch_bounds__(256,2)
// so zr[64] stays in VGPRs (round 1 showed VGPR_Count=56 => z was reloaded).
// Single-block k_codes split into k_newemb (256 blocks) + k_scalars (1 block).
// All rounding-sensitive fp ops kept bit-identical to the passing round-1 code.

#define KP 4

// ---- ws layout (bytes) ----
#define WS_ROW   0        // u64 wsrow[65536]  packed (ord(d)<<32)|~k
#define WS_COL   524288   // u64 wscol[1024]   packed (ord(d)<<32)|~n
#define WS_CNT   532480   // u32 counts[1024]
#define WS_LOSS  536576   // double loss_acc
#define WS_EN2   536592   // float en2[1024]
#define WS_BYTES 540688

__device__ __forceinline__ unsigned int f32_ord(float x) {
    unsigned int b = __float_as_uint(x);
    return (b & 0x80000000u) ? ~b : (b | 0x80000000u);
}

// numpy pairwise sum of squares over 64 contiguous values (8 strided chains,
// then ((r0+r1)+(r2+r3))+((r4+r5)+(r6+r7))), fp32, no contraction.
template <typename F>
__device__ __forceinline__ float np_pairwise64_sq(F get) {
    float r[8];
#pragma unroll
    for (int j = 0; j < 8; ++j) {
        float v = get(j);
        r[j] = __fmul_rn(v, v);
    }
#pragma unroll
    for (int i = 8; i < 64; i += 8) {
#pragma unroll
        for (int j = 0; j < 8; ++j) {
            float v = get(i + j);
            r[j] = __fadd_rn(r[j], __fmul_rn(v, v));
        }
    }
    return __fadd_rn(__fadd_rn(__fadd_rn(r[0], r[1]), __fadd_rn(r[2], r[3])),
                     __fadd_rn(__fadd_rn(r[4], r[5]), __fadd_rn(r[6], r[7])));
}

// ---- K0: codebook squared norms ----
__global__ __launch_bounds__(256) void k_en2(const float* __restrict__ emb,
                                             float* __restrict__ en2) {
    int k = blockIdx.x * 256 + threadIdx.x;
    const float* a = emb + (size_t)k * 64;
    en2[k] = np_pairwise64_sq([&](int i) { return a[i]; });
}

// ---- K1: score matrix + row/col argmax ----
// grid (256 token-blocks, KP code-partitions), block 256 = 4 waves.
// Thread = 1 token (z in 64 VGPRs). Embedding reads wave-uniform -> scalar.
// Column argmax: per-wave LDS tile [64 tokens][32 codes], stride 33.
__global__ __launch_bounds__(256, 2) void k_scores(
    const float* __restrict__ z, const float* __restrict__ emb,
    const float* __restrict__ en2,
    unsigned long long* __restrict__ wsrow,
    unsigned long long* __restrict__ wscol) {
    const int t    = threadIdx.x;
    const int lane = t & 63;
    const int wave = t >> 6;
    const int n    = blockIdx.x * 256 + t;
    const int k0   = blockIdx.y * 256;
    const int b    = n >> 12;
    const int hw   = n & 4095;

    __shared__ float tile[4][64 * 33];            // 33792 B, per-wave slabs
    __shared__ unsigned long long kbuf[4][32];    // 1 KB

    const float* zp = z + (size_t)b * 262144 + hw;
    float zr[64];
#pragma unroll
    for (int c = 0; c < 64; ++c) zr[c] = zp[(size_t)c * 4096];

    const float nzn2 = -np_pairwise64_sq([&](int i) { return zr[i]; });

    float bestv = -3.4e38f;
    int   bestk = k0;

    const float4* E4 = reinterpret_cast<const float4*>(emb);
    float* mytile = tile[wave];

    for (int g = 0; g < 8; ++g) {
        const int kg = k0 + g * 32;

        for (int kk = 0; kk < 32; ++kk) {
            const int k = kg + kk;
            const float4* ek = E4 + (size_t)k * 16;   // wave-uniform -> s_load
            float c0 = 0.f, c1 = 0.f, c2 = 0.f, c3 = 0.f;
#pragma unroll
            for (int j = 0; j < 16; ++j) {
                float4 e = ek[j];
                c0 = fmaf(e.x, zr[4 * j + 0], c0);
                c1 = fmaf(e.y, zr[4 * j + 1], c1);
                c2 = fmaf(e.z, zr[4 * j + 2], c2);
                c3 = fmaf(e.w, zr[4 * j + 3], c3);
            }
            float dot = (c0 + c1) + (c2 + c3);
            // d = ((-zn2) - en2) + 2*dot, per-op fp32 like numpy
            float d = __fadd_rn(__fsub_rn(nzn2, en2[k]), 2.0f * dot);

            // row argmax: ascending k, strict > == first-index ties
            if (d > bestv) { bestv = d; bestk = k; }

            // stash for column reduction: bank (lane+kk)&31 -> 2-way, free
            mytile[lane * 33 + kk] = d;
        }
        __syncthreads();  // also orders tile writes vs cross-lane reads

        // column reduce: lane owns code c=lane&31, half h=lane>>5 (32 tokens)
        {
            const int c = lane & 31, h = lane >> 5;
            const float* col = mytile + (h * 32) * 33 + c;
            float bv = col[0];
            int   bt = 0;
#pragma unroll
            for (int tt = 1; tt < 32; ++tt) {
                float v = col[(size_t)tt * 33];
                if (v > bv) { bv = v; bt = tt; }   // ascending token, strict >
            }
            int nwin = blockIdx.x * 256 + wave * 64 + h * 32 + bt;
            unsigned long long key =
                ((unsigned long long)f32_ord(bv) << 32) |
                (unsigned long long)(unsigned int)(~(unsigned int)nwin);
            unsigned long long other = __shfl_xor(key, 32, 64);
            if (other > key) key = other;          // ties: larger key = smaller n
            if (h == 0) kbuf[wave][c] = key;
        }
        __syncthreads();
        if (t < 32) {
            unsigned long long m = kbuf[0][t];
#pragma unroll
            for (int w = 1; w < 4; ++w) {
                unsigned long long o = kbuf[w][t];
                m = (o > m) ? o : m;
            }
            atomicMax(&wscol[kg + t], m);
        }
        __syncthreads();
    }

    unsigned long long rowkey =
        ((unsigned long long)f32_ord(bestv) << 32) |
        (unsigned long long)(unsigned int)(~(unsigned int)bestk);
    atomicMax(&wsrow[n], rowkey);
}

// ---- K2: per-token outputs: z_q (straight-through), indices, hist, loss ----
__global__ __launch_bounds__(256) void k_tokens(
    const float* __restrict__ z, const float* __restrict__ emb,
    const unsigned long long* __restrict__ wsrow,
    unsigned int* __restrict__ counts, double* __restrict__ loss_acc,
    float* __restrict__ out_zq, float* __restrict__ out_idx) {
    const int n  = blockIdx.x * 256 + threadIdx.x;
    const int b  = n >> 12;
    const int hw = n & 4095;

    unsigned long long key = wsrow[n];
    int idx = (int)(~(unsigned int)(key & 0xFFFFFFFFull));
    out_idx[n] = (float)idx;
    atomicAdd(&counts[idx], 1u);

    const float* zp = z + (size_t)b * 262144 + hw;
    float*       op = out_zq + (size_t)b * 262144 + hw;
    const float* ep = emb + (size_t)idx * 64;

    double ls = 0.0;
#pragma unroll
    for (int c = 0; c < 64; ++c) {
        float zc   = zp[(size_t)c * 4096];
        float eq   = ep[c];
        float diff = __fsub_rn(eq, zc);              // fl(z_q - zc)
        float sq   = __fmul_rn(diff, diff);
        ls += (double)sq;
        op[(size_t)c * 4096] = __fadd_rn(zc, diff);  // zc + fl(z_q - zc)
    }

    __shared__ double sred[256];
    sred[threadIdx.x] = ls;
    __syncthreads();
    for (int st = 128; st; st >>= 1) {
        if (threadIdx.x < st) sred[threadIdx.x] += sred[threadIdx.x + st];
        __syncthreads();
    }
    if (threadIdx.x == 0) atomicAdd(loss_acc, sred[0]);
}

// ---- K3a: scalars (loss, perplexity, embed_prob) — tiny, 1 block ----
__global__ __launch_bounds__(1024) void k_scalars(
    const float* __restrict__ embed_prob,
    const unsigned int* __restrict__ counts,
    const double* __restrict__ loss_acc,
    float* __restrict__ out_loss, float* __restrict__ out_perp,
    float* __restrict__ out_prob) {
    const int k = threadIdx.x;

    float avg  = (float)counts[k] * (1.0f / 65536.0f);
    float pnew = __fadd_rn(__fmul_rn(embed_prob[k], 0.99f),
                           __fmul_rn(0.01f, avg));
    out_prob[k] = pnew;

    float term = __fmul_rn(avg, logf(__fadd_rn(avg, 1e-10f)));
    __shared__ double red[1024];
    red[k] = (double)term;
    __syncthreads();
    for (int st = 512; st; st >>= 1) {
        if (k < st) red[k] += red[k + st];
        __syncthreads();
    }
    if (k == 0) {
        float s32 = (float)red[0];
        out_perp[0] = expf(-s32);
        double lm = loss_acc[0] / 4194304.0;
        float  m  = (float)lm;
        out_loss[0] = __fadd_rn(__fmul_rn(0.25f, m), m);  // BETA*m + m
    }
}

// ---- K3b: new embedding — thread = (code, channel), 256 blocks ----
__global__ __launch_bounds__(256) void k_newemb(
    const float* __restrict__ z, const float* __restrict__ emb,
    const float* __restrict__ embed_prob,
    const unsigned long long* __restrict__ wscol,
    const unsigned int* __restrict__ counts,
    float* __restrict__ out_newemb) {
    const int k = blockIdx.x * 4 + (threadIdx.x >> 6);
    const int c = threadIdx.x & 63;

    // recompute pnew/decay with ops identical to k_scalars (bit-equal)
    float avg  = (float)counts[k] * (1.0f / 65536.0f);
    float pnew = __fadd_rn(__fmul_rn(embed_prob[k], 0.99f),
                           __fmul_rn(0.01f, avg));
    float tt = __fdiv_rn(__fmul_rn(__fmul_rn(pnew, 1024.0f), 10.0f), 0.01f);
    float dk = expf(__fsub_rn(-tt, 1e-3f));
    float omd = __fsub_rn(1.0f, dk);

    unsigned long long ck = wscol[k];
    int cn  = (int)(~(unsigned int)(ck & 0xFFFFFFFFull));
    int cb  = cn >> 12;
    int chw = cn & 4095;

    float rf = z[(size_t)cb * 262144 + (size_t)c * 4096 + chw];
    float e  = emb[(size_t)k * 64 + c];
    out_newemb[(size_t)k * 64 + c] =
        __fadd_rn(__fmul_rn(e, omd), __fmul_rn(rf, dk));
}

extern "C" void kernel_launch(void* const* d_in, const int* in_sizes, int n_in,
                              void* d_out, int out_size, void* d_ws, size_t ws_size,
                              hipStream_t stream) {
    const float* z    = (const float*)d_in[0];   // 16*64*64*64
    const float* emb  = (const float*)d_in[1];   // 1024*64
    const float* prob = (const float*)d_in[2];   // 1024

    float* out        = (float*)d_out;
    float* out_zq     = out;                 // 4194304
    float* out_loss   = out + 4194304;       // 1
    float* out_perp   = out + 4194305;       // 1
    float* out_newemb = out + 4194306;       // 65536
    float* out_prob   = out + 4259842;       // 1024
    float* out_idx    = out + 4260866;       // 65536

    char* ws = (char*)d_ws;
    unsigned long long* wsrow = (unsigned long long*)(ws + WS_ROW);
    unsigned long long* wscol = (unsigned long long*)(ws + WS_COL);
    unsigned int*       cnts  = (unsigned int*)(ws + WS_CNT);
    double*             lacc  = (double*)(ws + WS_LOSS);
    float*              en2   = (float*)(ws + WS_EN2);

    hipMemsetAsync(d_ws, 0, WS_BYTES, stream);

    hipLaunchKernelGGL(k_en2, dim3(4), dim3(256), 0, stream, emb, en2);
    hipLaunchKernelGGL(k_scores, dim3(256, KP), dim3(256), 0, stream,
                       z, emb, en2, wsrow, wscol);
    hipLaunchKernelGGL(k_tokens, dim3(256), dim3(256), 0, stream,
                       z, emb, wsrow, cnts, lacc, out_zq, out_idx);
    hipLaunchKernelGGL(k_scalars, dim3(1), dim3(1024), 0, stream,
                       prob, cnts, lacc, out_loss, out_perp, out_prob);
    hipLaunchKernelGGL(k_newemb, dim3(256), dim3(256), 0, stream,
                       z, emb, prob, wscol, cnts, out_newemb);
}